// Round 1
// baseline (1926.066 us; speedup 1.0000x reference)
//
#include <hip/hip_runtime.h>
#include <math.h>

// Problem constants (from reference)
#define N_NODES 50000
#define N_EDGES 800000
#define HID 128

// ---------------------------------------------------------------------------
// ws layout (floats):
//   F1t   [128*128]  : transposed fold of node_W @ enc_W[:128]
//   F2t   [128*128]  : transposed fold of nbr_W  @ enc_W[128:256]
//   F3t   [128*128]  : transposed fold of gud_W  @ enc_W[256:384]
//   c     [128]      : folded biases
//   vpW1t [64*128]   : vp_W1 transposed  (row j = column j of vp_W1)
//   polW1t[128*128]  : pol_W1 transposed
//   P     [N_NODES*128]
//   Q     [N_NODES*128]
// total ~51.5 MB
// ---------------------------------------------------------------------------

// Fold the three front-end linears + encoder into per-node matrices.
// F1t[j*128+k] = sum_m node_W[k][m] * enc_W[m][j]   (and similarly F2t/F3t)
__global__ __launch_bounds__(128) void fold_kernel(
    const float* __restrict__ node_W, const float* __restrict__ node_b,
    const float* __restrict__ nbr_W,  const float* __restrict__ nbr_b,
    const float* __restrict__ gud_W,  const float* __restrict__ gud_b,
    const float* __restrict__ enc_W,  const float* __restrict__ enc_b,
    float* __restrict__ F1t, float* __restrict__ F2t, float* __restrict__ F3t,
    float* __restrict__ c)
{
    int j = blockIdx.x;   // output channel 0..127
    int k = threadIdx.x;  // input channel  0..127
    float a0 = 0.f, a1 = 0.f, a2 = 0.f;
    #pragma unroll 4
    for (int m = 0; m < 128; ++m) {
        float e1 = enc_W[m * 128 + j];
        float e2 = enc_W[(128 + m) * 128 + j];
        float e3 = enc_W[(256 + m) * 128 + j];
        a0 = fmaf(node_W[k * 128 + m], e1, a0);
        a1 = fmaf(nbr_W [k * 128 + m], e2, a1);
        a2 = fmaf(gud_W [k * 128 + m], e3, a2);
    }
    F1t[j * 128 + k] = a0;
    F2t[j * 128 + k] = a1;
    F3t[j * 128 + k] = a2;
    if (k == 0) {
        float cc = enc_b[j];
        for (int m = 0; m < 128; ++m) {
            cc = fmaf(node_b[m], enc_W[m * 128 + j], cc);
            cc = fmaf(nbr_b [m], enc_W[(128 + m) * 128 + j], cc);
            cc = fmaf(gud_b [m], enc_W[(256 + m) * 128 + j], cc);
        }
        c[j] = cc;
    }
}

// Transpose the two head weight matrices so the per-edge inner loops read
// contiguous (scalar-cacheable) 128-float rows.
__global__ __launch_bounds__(256) void transpose_kernel(
    const float* __restrict__ vp_W1, const float* __restrict__ pol_W1,
    float* __restrict__ vpW1t, float* __restrict__ polW1t)
{
    int t = blockIdx.x * 256 + threadIdx.x;  // 0..24575 (exact: 96*256)
    if (t < 64 * 128) {
        int j = t / 128, k = t % 128;
        vpW1t[t] = vp_W1[k * 64 + j];
    } else {
        int u = t - 64 * 128;
        int j = u / 128, k = u % 128;
        polW1t[u] = pol_W1[k * 128 + j];
    }
}

// Per-node precompute: P = x @ F1, Q = x @ F2 + g @ F3
__global__ __launch_bounds__(256, 2) void node_kernel(
    const float* __restrict__ x, const float* __restrict__ g,
    const float* __restrict__ F1t, const float* __restrict__ F2t,
    const float* __restrict__ F3t,
    float* __restrict__ P, float* __restrict__ Q)
{
    int n0 = blockIdx.x * 256 + threadIdx.x;
    bool valid = (n0 < N_NODES);
    int n = valid ? n0 : (N_NODES - 1);   // clamp loads, guard stores (keeps
                                          // control flow uniform for scalar
                                          // promotion of weight loads)
    float xr[128];
    {
        const float4* xp = (const float4*)(x + (size_t)n * 128);
        #pragma unroll
        for (int k4 = 0; k4 < 32; ++k4) {
            float4 v = xp[k4];
            xr[4 * k4 + 0] = v.x; xr[4 * k4 + 1] = v.y;
            xr[4 * k4 + 2] = v.z; xr[4 * k4 + 3] = v.w;
        }
    }
    #pragma unroll 1
    for (int j = 0; j < 128; ++j) {
        const float* w1 = F1t + j * 128;
        const float* w2 = F2t + j * 128;
        float p0 = 0.f, p1 = 0.f, q0 = 0.f, q1 = 0.f;
        #pragma unroll
        for (int k = 0; k < 64; ++k) {
            p0 = fmaf(xr[k],      w1[k],      p0);
            p1 = fmaf(xr[64 + k], w1[64 + k], p1);
            q0 = fmaf(xr[k],      w2[k],      q0);
            q1 = fmaf(xr[64 + k], w2[64 + k], q1);
        }
        if (valid) {
            P[(size_t)n * 128 + j] = p0 + p1;
            Q[(size_t)n * 128 + j] = q0 + q1;
        }
    }
    // phase 2: guidance contribution to Q
    {
        const float4* gp = (const float4*)(g + (size_t)n * 128);
        #pragma unroll
        for (int k4 = 0; k4 < 32; ++k4) {
            float4 v = gp[k4];
            xr[4 * k4 + 0] = v.x; xr[4 * k4 + 1] = v.y;
            xr[4 * k4 + 2] = v.z; xr[4 * k4 + 3] = v.w;
        }
    }
    #pragma unroll 1
    for (int j = 0; j < 128; ++j) {
        const float* w3 = F3t + j * 128;
        float q0 = 0.f, q1 = 0.f;
        #pragma unroll
        for (int k = 0; k < 64; ++k) {
            q0 = fmaf(xr[k],      w3[k],      q0);
            q1 = fmaf(xr[64 + k], w3[64 + k], q1);
        }
        if (valid) Q[(size_t)n * 128 + j] += q0 + q1;
    }
}

// Per-edge: enc = relu(P[row]+Q[col]+c); two MLP heads.
// 800000 = 3125 * 256 exactly -> no bounds guard, fully uniform control flow.
__global__ __launch_bounds__(256, 2) void edge_kernel(
    const int* __restrict__ ei,
    const float* __restrict__ P, const float* __restrict__ Q,
    const float* __restrict__ c,
    const float* __restrict__ vpW1t, const float* __restrict__ vp_b1,
    const float* __restrict__ vp_W2, const float* __restrict__ vp_b2,
    const float* __restrict__ polW1t, const float* __restrict__ pol_b1,
    const float* __restrict__ pol_W2, const float* __restrict__ pol_b2,
    float* __restrict__ out)
{
    int e = blockIdx.x * 256 + threadIdx.x;
    int row = ei[e];
    int col = ei[N_EDGES + e];

    float enc[128];
    {
        const float4* Pr = (const float4*)(P + (size_t)row * 128);
        const float4* Qr = (const float4*)(Q + (size_t)col * 128);
        const float4* cr = (const float4*)c;
        #pragma unroll
        for (int k4 = 0; k4 < 32; ++k4) {
            float4 a = Pr[k4];
            float4 b = Qr[k4];
            float4 cc = cr[k4];
            enc[4 * k4 + 0] = fmaxf(a.x + b.x + cc.x, 0.f);
            enc[4 * k4 + 1] = fmaxf(a.y + b.y + cc.y, 0.f);
            enc[4 * k4 + 2] = fmaxf(a.z + b.z + cc.z, 0.f);
            enc[4 * k4 + 3] = fmaxf(a.w + b.w + cc.w, 0.f);
        }
    }

    // value head: relu(enc @ vp_W1 + vp_b1) @ vp_W2 + vp_b2
    float value = 0.f;
    #pragma unroll 1
    for (int j = 0; j < 64; ++j) {
        const float* w = vpW1t + j * 128;
        float h0 = 0.f, h1 = 0.f;
        #pragma unroll
        for (int k = 0; k < 64; ++k) {
            h0 = fmaf(enc[k],      w[k],      h0);
            h1 = fmaf(enc[64 + k], w[64 + k], h1);
        }
        float h = fmaxf(h0 + h1 + vp_b1[j], 0.f);
        value = fmaf(h, vp_W2[j], value);
    }
    value += vp_b2[0];

    // policy head: sigmoid(relu(enc @ pol_W1 + pol_b1) @ pol_W2 + pol_b2)
    float logit = 0.f;
    #pragma unroll 1
    for (int j = 0; j < 128; ++j) {
        const float* w = polW1t + j * 128;
        float h0 = 0.f, h1 = 0.f;
        #pragma unroll
        for (int k = 0; k < 64; ++k) {
            h0 = fmaf(enc[k],      w[k],      h0);
            h1 = fmaf(enc[64 + k], w[64 + k], h1);
        }
        float h = fmaxf(h0 + h1 + pol_b1[j], 0.f);
        logit = fmaf(h, pol_W2[j], logit);
    }
    logit += pol_b2[0];

    float prob = 1.0f / (1.0f + expf(-logit));

    out[e] = value;                                  // value_preds
    out[N_EDGES + e] = prob;                         // action_probs
    out[2 * N_EDGES + e] = (prob > 0.5f) ? 1.f : 0.f; // actions
    if (e == 0) out[3 * N_EDGES] = 0.f;              // value_loss (eval mode)
}

extern "C" void kernel_launch(void* const* d_in, const int* in_sizes, int n_in,
                              void* d_out, int out_size, void* d_ws, size_t ws_size,
                              hipStream_t stream) {
    const float* x      = (const float*)d_in[0];
    const int*   ei     = (const int*)  d_in[1];
    const float* gf     = (const float*)d_in[2];
    const float* node_W = (const float*)d_in[3];
    const float* node_b = (const float*)d_in[4];
    const float* nbr_W  = (const float*)d_in[5];
    const float* nbr_b  = (const float*)d_in[6];
    const float* gud_W  = (const float*)d_in[7];
    const float* gud_b  = (const float*)d_in[8];
    const float* enc_W  = (const float*)d_in[9];
    const float* enc_b  = (const float*)d_in[10];
    const float* vp_W1  = (const float*)d_in[11];
    const float* vp_b1  = (const float*)d_in[12];
    const float* vp_W2  = (const float*)d_in[13];
    const float* vp_b2  = (const float*)d_in[14];
    const float* pol_W1 = (const float*)d_in[15];
    const float* pol_b1 = (const float*)d_in[16];
    const float* pol_W2 = (const float*)d_in[17];
    const float* pol_b2 = (const float*)d_in[18];
    float* out = (float*)d_out;

    float* ws = (float*)d_ws;
    float* F1t    = ws;                 // 16384
    float* F2t    = F1t + 128 * 128;    // 16384
    float* F3t    = F2t + 128 * 128;    // 16384
    float* c      = F3t + 128 * 128;    // 128
    float* vpW1t  = c + 128;            // 8192
    float* polW1t = vpW1t + 64 * 128;   // 16384
    float* P      = polW1t + 128 * 128; // 6.4M
    float* Q      = P + (size_t)N_NODES * 128;

    fold_kernel<<<dim3(128), dim3(128), 0, stream>>>(
        node_W, node_b, nbr_W, nbr_b, gud_W, gud_b, enc_W, enc_b,
        F1t, F2t, F3t, c);

    transpose_kernel<<<dim3(96), dim3(256), 0, stream>>>(
        vp_W1, pol_W1, vpW1t, polW1t);

    node_kernel<<<dim3((N_NODES + 255) / 256), dim3(256), 0, stream>>>(
        x, gf, F1t, F2t, F3t, P, Q);

    edge_kernel<<<dim3(N_EDGES / 256), dim3(256), 0, stream>>>(
        ei, P, Q, c, vpW1t, vp_b1, vp_W2, vp_b2,
        polW1t, pol_b1, pol_W2, pol_b2, out);
}

// Round 2
// 689.599 us; speedup vs baseline: 2.7930x; 2.7930x over previous
//
#include <hip/hip_runtime.h>
#include <math.h>

#define N_NODES 50000
#define N_EDGES 800000

// ---------------------------------------------------------------------------
// ws layout (floats):
//   Wa  [128*256] k-major combined: col j<128 -> F1 = node_W@encW[:128]
//                                   col j>=128 -> F2 = nbr_W@encW[128:256]
//   Wb  [128*128] k-major: F3 = gud_W@encW[256:384]
//   W1c [128*192] k-major combined head W1: J<64 -> vp_W1, J>=64 -> pol_W1
//   cb  [128]     folded bias: node_b@E1 + nbr_b@E2 + gud_b@E3 + enc_b
//   P   [N_NODES*128] = x @ F1
//   Q   [N_NODES*128] = x @ F2 + g @ F3
// ---------------------------------------------------------------------------

__global__ __launch_bounds__(256) void prep_kernel(
    const float* __restrict__ node_W, const float* __restrict__ node_b,
    const float* __restrict__ nbr_W,  const float* __restrict__ nbr_b,
    const float* __restrict__ gud_W,  const float* __restrict__ gud_b,
    const float* __restrict__ enc_W,  const float* __restrict__ enc_b,
    const float* __restrict__ vp_W1,  const float* __restrict__ pol_W1,
    float* __restrict__ Wa, float* __restrict__ Wb,
    float* __restrict__ W1c, float* __restrict__ cb)
{
    const int k = blockIdx.x;    // 0..127
    const int j = threadIdx.x;   // 0..255
    if (j < 128) {
        float a = 0.f, b = 0.f;
        #pragma unroll 4
        for (int m = 0; m < 128; ++m) {
            a = fmaf(node_W[k * 128 + m], enc_W[m * 128 + j], a);
            b = fmaf(gud_W [k * 128 + m], enc_W[(256 + m) * 128 + j], b);
        }
        Wa[k * 256 + j] = a;
        Wb[k * 128 + j] = b;
    } else {
        const int jj = j - 128;
        float a = 0.f;
        #pragma unroll 4
        for (int m = 0; m < 128; ++m)
            a = fmaf(nbr_W[k * 128 + m], enc_W[(128 + m) * 128 + jj], a);
        Wa[k * 256 + j] = a;
    }
    if (j < 192)
        W1c[k * 192 + j] = (j < 64) ? vp_W1[k * 64 + j] : pol_W1[k * 128 + (j - 64)];
    if (k == 0 && j < 128) {
        float cc = enc_b[j];
        for (int m = 0; m < 128; ++m) {
            cc = fmaf(node_b[m], enc_W[m * 128 + j], cc);
            cc = fmaf(nbr_b [m], enc_W[(128 + m) * 128 + j], cc);
            cc = fmaf(gud_b [m], enc_W[(256 + m) * 128 + j], cc);
        }
        cb[j] = cc;
    }
}

// ---------------------------------------------------------------------------
// node_kernel: per-node GEMM  [64 nodes] x (x@[F1|F2] then g@F3)
// 256 threads = 16 tx (channels, 4 strided groups of 4) x 16 ty (4 nodes each)
// ---------------------------------------------------------------------------
__global__ __launch_bounds__(256, 3) void node_kernel(
    const float* __restrict__ x, const float* __restrict__ g,
    const float* __restrict__ Wa, const float* __restrict__ Wb,
    float* __restrict__ P, float* __restrict__ Q)
{
    __shared__ float a_s[64 * 132];
    __shared__ float w_s[16 * 256];
    const int t  = threadIdx.x;
    const int tx = t & 15, ty = t >> 4;
    const int base = blockIdx.x * 64;

    // stage x rows (clamped at tail)
    {
        const int grp = t >> 5, ch4 = (t & 31) * 4;
        #pragma unroll 1
        for (int i = 0; i < 8; ++i) {
            int nl = i * 8 + grp;
            int n = base + nl; if (n >= N_NODES) n = N_NODES - 1;
            *(float4*)(a_s + nl * 132 + ch4) =
                *(const float4*)(x + (size_t)n * 128 + ch4);
        }
    }

    float acc[4][16];
    #pragma unroll
    for (int i = 0; i < 4; ++i)
        #pragma unroll
        for (int c = 0; c < 16; ++c) acc[i][c] = 0.f;

    // part 1: x @ [F1|F2]  (all 4 channel groups)
    for (int kc = 0; kc < 8; ++kc) {
        __syncthreads();
        {   // stage Wa rows kc*16..+15 : 4096 floats = 1024 float4
            const float4* src = (const float4*)(Wa + kc * 16 * 256);
            float4* dst = (float4*)w_s;
            dst[t] = src[t]; dst[t + 256] = src[t + 256];
            dst[t + 512] = src[t + 512]; dst[t + 768] = src[t + 768];
        }
        __syncthreads();
        #pragma unroll 1
        for (int kk = 0; kk < 16; kk += 2) {
            const int k = kc * 16 + kk;
            float2 a01[4];
            #pragma unroll
            for (int i = 0; i < 4; ++i)
                a01[i] = *(const float2*)(a_s + (ty * 4 + i) * 132 + k);
            float4 w0[4], w1[4];
            #pragma unroll
            for (int gi = 0; gi < 4; ++gi) {
                w0[gi] = *(const float4*)(w_s + kk * 256 + gi * 64 + tx * 4);
                w1[gi] = *(const float4*)(w_s + (kk + 1) * 256 + gi * 64 + tx * 4);
            }
            #pragma unroll
            for (int i = 0; i < 4; ++i)
                #pragma unroll
                for (int gi = 0; gi < 4; ++gi) {
                    acc[i][gi*4+0] = fmaf(a01[i].x, w0[gi].x, acc[i][gi*4+0]);
                    acc[i][gi*4+1] = fmaf(a01[i].x, w0[gi].y, acc[i][gi*4+1]);
                    acc[i][gi*4+2] = fmaf(a01[i].x, w0[gi].z, acc[i][gi*4+2]);
                    acc[i][gi*4+3] = fmaf(a01[i].x, w0[gi].w, acc[i][gi*4+3]);
                    acc[i][gi*4+0] = fmaf(a01[i].y, w1[gi].x, acc[i][gi*4+0]);
                    acc[i][gi*4+1] = fmaf(a01[i].y, w1[gi].y, acc[i][gi*4+1]);
                    acc[i][gi*4+2] = fmaf(a01[i].y, w1[gi].z, acc[i][gi*4+2]);
                    acc[i][gi*4+3] = fmaf(a01[i].y, w1[gi].w, acc[i][gi*4+3]);
                }
        }
    }

    // restage g rows
    __syncthreads();
    {
        const int grp = t >> 5, ch4 = (t & 31) * 4;
        #pragma unroll 1
        for (int i = 0; i < 8; ++i) {
            int nl = i * 8 + grp;
            int n = base + nl; if (n >= N_NODES) n = N_NODES - 1;
            *(float4*)(a_s + nl * 132 + ch4) =
                *(const float4*)(g + (size_t)n * 128 + ch4);
        }
    }

    // part 2: g @ F3  (channel groups 2,3 only -> Q)
    for (int kc = 0; kc < 8; ++kc) {
        __syncthreads();
        {   // stage Wb rows kc*16..+15 : 2048 floats = 512 float4
            const float4* src = (const float4*)(Wb + kc * 16 * 128);
            float4* dst = (float4*)w_s;
            dst[t] = src[t]; dst[t + 256] = src[t + 256];
        }
        __syncthreads();
        #pragma unroll 1
        for (int kk = 0; kk < 16; kk += 2) {
            const int k = kc * 16 + kk;
            float2 a01[4];
            #pragma unroll
            for (int i = 0; i < 4; ++i)
                a01[i] = *(const float2*)(a_s + (ty * 4 + i) * 132 + k);
            float4 w0[2], w1[2];
            #pragma unroll
            for (int gi = 0; gi < 2; ++gi) {
                w0[gi] = *(const float4*)(w_s + kk * 128 + gi * 64 + tx * 4);
                w1[gi] = *(const float4*)(w_s + (kk + 1) * 128 + gi * 64 + tx * 4);
            }
            #pragma unroll
            for (int i = 0; i < 4; ++i)
                #pragma unroll
                for (int gi = 0; gi < 2; ++gi) {
                    const int cb_ = 8 + gi * 4;
                    acc[i][cb_+0] = fmaf(a01[i].x, w0[gi].x, acc[i][cb_+0]);
                    acc[i][cb_+1] = fmaf(a01[i].x, w0[gi].y, acc[i][cb_+1]);
                    acc[i][cb_+2] = fmaf(a01[i].x, w0[gi].z, acc[i][cb_+2]);
                    acc[i][cb_+3] = fmaf(a01[i].x, w0[gi].w, acc[i][cb_+3]);
                    acc[i][cb_+0] = fmaf(a01[i].y, w1[gi].x, acc[i][cb_+0]);
                    acc[i][cb_+1] = fmaf(a01[i].y, w1[gi].y, acc[i][cb_+1]);
                    acc[i][cb_+2] = fmaf(a01[i].y, w1[gi].z, acc[i][cb_+2]);
                    acc[i][cb_+3] = fmaf(a01[i].y, w1[gi].w, acc[i][cb_+3]);
                }
        }
    }

    // stores: groups 0,1 -> P ; groups 2,3 -> Q
    #pragma unroll
    for (int i = 0; i < 4; ++i) {
        int n = base + ty * 4 + i;
        if (n < N_NODES) {
            *(float4*)(P + (size_t)n * 128 + tx * 4)      = make_float4(acc[i][0], acc[i][1], acc[i][2], acc[i][3]);
            *(float4*)(P + (size_t)n * 128 + 64 + tx * 4) = make_float4(acc[i][4], acc[i][5], acc[i][6], acc[i][7]);
            *(float4*)(Q + (size_t)n * 128 + tx * 4)      = make_float4(acc[i][8], acc[i][9], acc[i][10], acc[i][11]);
            *(float4*)(Q + (size_t)n * 128 + 64 + tx * 4) = make_float4(acc[i][12], acc[i][13], acc[i][14], acc[i][15]);
        }
    }
}

// ---------------------------------------------------------------------------
// edge_kernel: block = 64 edges. Phase1 gather->relu->LDS. Phase2 GEMM
// C[64x192] = ENC @ W1c. Epilogue: bias/relu/W2 dot + shfl reduce.
// Thread (ty,tx): 4 edges (ty*4..) x 12 channels {tx*4, 64+tx*4, 128+tx*4}.
// 800000 = 12500 * 64 exactly.
// ---------------------------------------------------------------------------
__global__ __launch_bounds__(256, 3) void edge_kernel(
    const int* __restrict__ ei,
    const float* __restrict__ P, const float* __restrict__ Q,
    const float* __restrict__ cb, const float* __restrict__ W1c,
    const float* __restrict__ vp_b1, const float* __restrict__ vp_W2,
    const float* __restrict__ vp_b2,
    const float* __restrict__ pol_b1, const float* __restrict__ pol_W2,
    const float* __restrict__ pol_b2,
    float* __restrict__ out)
{
    __shared__ float enc_s[64 * 132];
    __shared__ float w_s[16 * 192];
    __shared__ int rows_s[64], cols_s[64];
    const int t  = threadIdx.x;
    const int tx = t & 15, ty = t >> 4;
    const int e0 = blockIdx.x * 64;

    if (t < 64) rows_s[t] = ei[e0 + t];
    else if (t < 128) cols_s[t - 64] = ei[N_EDGES + e0 + (t - 64)];

    // preload head biases / W2 columns for this thread's channels
    float vb[4], vw[4], pb0[4], pw0[4], pb1[4], pw1[4];
    #pragma unroll
    for (int j = 0; j < 4; ++j) {
        vb[j]  = vp_b1[tx * 4 + j];       vw[j]  = vp_W2[tx * 4 + j];
        pb0[j] = pol_b1[tx * 4 + j];      pw0[j] = pol_W2[tx * 4 + j];
        pb1[j] = pol_b1[64 + tx * 4 + j]; pw1[j] = pol_W2[64 + tx * 4 + j];
    }
    const float vb2 = vp_b2[0], pb2 = pol_b2[0];

    __syncthreads();

    // phase 1: gather P[row]+Q[col]+cb -> relu -> enc_s
    {
        const int grp = t >> 5, ch4 = (t & 31) * 4;
        const float4 c4 = *(const float4*)(cb + ch4);
        #pragma unroll 1
        for (int i = 0; i < 8; ++i) {
            int el = i * 8 + grp;
            int r  = rows_s[el];
            int cI = cols_s[el];
            float4 p4 = *(const float4*)(P + (size_t)r  * 128 + ch4);
            float4 q4 = *(const float4*)(Q + (size_t)cI * 128 + ch4);
            float4 e4;
            e4.x = fmaxf(p4.x + q4.x + c4.x, 0.f);
            e4.y = fmaxf(p4.y + q4.y + c4.y, 0.f);
            e4.z = fmaxf(p4.z + q4.z + c4.z, 0.f);
            e4.w = fmaxf(p4.w + q4.w + c4.w, 0.f);
            *(float4*)(enc_s + el * 132 + ch4) = e4;
        }
    }

    float acc[4][12];
    #pragma unroll
    for (int i = 0; i < 4; ++i)
        #pragma unroll
        for (int c = 0; c < 12; ++c) acc[i][c] = 0.f;

    for (int kc = 0; kc < 8; ++kc) {
        __syncthreads();
        {   // stage W1c rows kc*16..+15 : 3072 floats = 768 float4
            const float4* src = (const float4*)(W1c + kc * 16 * 192);
            float4* dst = (float4*)w_s;
            dst[t] = src[t]; dst[t + 256] = src[t + 256]; dst[t + 512] = src[t + 512];
        }
        __syncthreads();
        #pragma unroll 1
        for (int kk = 0; kk < 16; kk += 2) {
            const int k = kc * 16 + kk;
            float2 a01[4];
            #pragma unroll
            for (int i = 0; i < 4; ++i)
                a01[i] = *(const float2*)(enc_s + (ty * 4 + i) * 132 + k);
            float4 w0[3], w1[3];
            #pragma unroll
            for (int gi = 0; gi < 3; ++gi) {
                w0[gi] = *(const float4*)(w_s + kk * 192 + gi * 64 + tx * 4);
                w1[gi] = *(const float4*)(w_s + (kk + 1) * 192 + gi * 64 + tx * 4);
            }
            #pragma unroll
            for (int i = 0; i < 4; ++i)
                #pragma unroll
                for (int gi = 0; gi < 3; ++gi) {
                    acc[i][gi*4+0] = fmaf(a01[i].x, w0[gi].x, acc[i][gi*4+0]);
                    acc[i][gi*4+1] = fmaf(a01[i].x, w0[gi].y, acc[i][gi*4+1]);
                    acc[i][gi*4+2] = fmaf(a01[i].x, w0[gi].z, acc[i][gi*4+2]);
                    acc[i][gi*4+3] = fmaf(a01[i].x, w0[gi].w, acc[i][gi*4+3]);
                    acc[i][gi*4+0] = fmaf(a01[i].y, w1[gi].x, acc[i][gi*4+0]);
                    acc[i][gi*4+1] = fmaf(a01[i].y, w1[gi].y, acc[i][gi*4+1]);
                    acc[i][gi*4+2] = fmaf(a01[i].y, w1[gi].z, acc[i][gi*4+2]);
                    acc[i][gi*4+3] = fmaf(a01[i].y, w1[gi].w, acc[i][gi*4+3]);
                }
        }
    }

    // epilogue: bias + relu + W2 dot, then reduce across the 16 tx lanes
    float vout[4], pout[4];
    #pragma unroll
    for (int i = 0; i < 4; ++i) {
        float v = 0.f, p = 0.f;
        #pragma unroll
        for (int j = 0; j < 4; ++j) {
            v = fmaf(fmaxf(acc[i][j]     + vb[j],  0.f), vw[j],  v);
            p = fmaf(fmaxf(acc[i][4 + j] + pb0[j], 0.f), pw0[j], p);
            p = fmaf(fmaxf(acc[i][8 + j] + pb1[j], 0.f), pw1[j], p);
        }
        #pragma unroll
        for (int off = 8; off; off >>= 1) {
            v += __shfl_down(v, off, 16);
            p += __shfl_down(p, off, 16);
        }
        vout[i] = v; pout[i] = p;
    }

    if (tx == 0) {
        #pragma unroll
        for (int i = 0; i < 4; ++i) {
            const int e = e0 + ty * 4 + i;
            const float value = vout[i] + vb2;
            const float logit = pout[i] + pb2;
            const float prob  = 1.0f / (1.0f + expf(-logit));
            out[e] = value;
            out[N_EDGES + e] = prob;
            out[2 * N_EDGES + e] = (prob > 0.5f) ? 1.f : 0.f;
        }
    }
    if (e0 == 0 && t == 0) out[3 * N_EDGES] = 0.f;
}

extern "C" void kernel_launch(void* const* d_in, const int* in_sizes, int n_in,
                              void* d_out, int out_size, void* d_ws, size_t ws_size,
                              hipStream_t stream) {
    const float* x      = (const float*)d_in[0];
    const int*   ei     = (const int*)  d_in[1];
    const float* gf     = (const float*)d_in[2];
    const float* node_W = (const float*)d_in[3];
    const float* node_b = (const float*)d_in[4];
    const float* nbr_W  = (const float*)d_in[5];
    const float* nbr_b  = (const float*)d_in[6];
    const float* gud_W  = (const float*)d_in[7];
    const float* gud_b  = (const float*)d_in[8];
    const float* enc_W  = (const float*)d_in[9];
    const float* enc_b  = (const float*)d_in[10];
    const float* vp_W1  = (const float*)d_in[11];
    const float* vp_b1  = (const float*)d_in[12];
    const float* vp_W2  = (const float*)d_in[13];
    const float* vp_b2  = (const float*)d_in[14];
    const float* pol_W1 = (const float*)d_in[15];
    const float* pol_b1 = (const float*)d_in[16];
    const float* pol_W2 = (const float*)d_in[17];
    const float* pol_b2 = (const float*)d_in[18];
    float* out = (float*)d_out;

    float* ws  = (float*)d_ws;
    float* Wa  = ws;                     // 32768
    float* Wb  = Wa + 128 * 256;         // 16384
    float* W1c = Wb + 128 * 128;         // 24576
    float* cbv = W1c + 128 * 192;        // 128
    float* P   = cbv + 128;              // 6.4M
    float* Q   = P + (size_t)N_NODES * 128;

    prep_kernel<<<dim3(128), dim3(256), 0, stream>>>(
        node_W, node_b, nbr_W, nbr_b, gud_W, gud_b, enc_W, enc_b,
        vp_W1, pol_W1, Wa, Wb, W1c, cbv);

    node_kernel<<<dim3((N_NODES + 63) / 64), dim3(256), 0, stream>>>(
        x, gf, Wa, Wb, P, Q);

    edge_kernel<<<dim3(N_EDGES / 64), dim3(256), 0, stream>>>(
        ei, P, Q, cbv, W1c, vp_b1, vp_W2, vp_b2,
        pol_b1, pol_W2, pol_b2, out);
}

// Round 5
// 588.819 us; speedup vs baseline: 3.2711x; 1.1712x over previous
//
#include <hip/hip_runtime.h>
#include <math.h>

#define N_NODES 50000
#define N_EDGES 800000

// fp32 = a0+a1+a2 (3 bf16 terms, 24 mantissa bits). 6 MFMA term-pairs per
// product -> fp32-class numerics on the bf16 matrix core.
typedef __attribute__((ext_vector_type(8))) short short8_t;   // bf16x8 (4 VGPR)
typedef __attribute__((ext_vector_type(4))) float float4_t;   // fp32x4 acc

union U8 { short8_t v; unsigned short u[8]; };

__device__ __forceinline__ unsigned short bf16_rn(float f) {
    unsigned u = __float_as_uint(f);
    u += 0x7fffu + ((u >> 16) & 1u);
    return (unsigned short)(u >> 16);
}
__device__ __forceinline__ float bf2f(unsigned short h) {
    return __uint_as_float((unsigned)h << 16);
}
__device__ __forceinline__ void split3(float f, unsigned short& s0,
                                       unsigned short& s1, unsigned short& s2) {
    s0 = bf16_rn(f);  float r = f - bf2f(s0);
    s1 = bf16_rn(r);  r -= bf2f(s1);
    s2 = bf16_rn(r);
}

// ---------------------------------------------------------------------------
// ws layout (bytes):
//   BTn0/1/2 [256][128] bf16 : rows 0..127 = F1^T (P), 128..255 = F2^T (Q,x)
//   BTg0/1/2 [128][128] bf16 : F3^T (Q,g)
//   BTw0/1/2 [192][128] bf16 : [vp_W1 | pol_W1]^T
//   cb[128] folded bias (into P), b1c[192], W2c[192], flags[16]
//   P[50000*128] = x@F1 + cb ; Q[50000*128] = x@F2 + g@F3
// ---------------------------------------------------------------------------

__global__ __launch_bounds__(256) void prep_kernel(
    const float* __restrict__ node_W, const float* __restrict__ node_b,
    const float* __restrict__ nbr_W,  const float* __restrict__ nbr_b,
    const float* __restrict__ gud_W,  const float* __restrict__ gud_b,
    const float* __restrict__ enc_W,  const float* __restrict__ enc_b,
    const float* __restrict__ vp_W1,  const float* __restrict__ vp_b1,
    const float* __restrict__ vp_W2,  const float* __restrict__ pol_W1,
    const float* __restrict__ pol_b1, const float* __restrict__ pol_W2,
    unsigned short* __restrict__ BTn0, unsigned short* __restrict__ BTn1,
    unsigned short* __restrict__ BTn2,
    unsigned short* __restrict__ BTg0, unsigned short* __restrict__ BTg1,
    unsigned short* __restrict__ BTg2,
    unsigned short* __restrict__ BTw0, unsigned short* __restrict__ BTw1,
    unsigned short* __restrict__ BTw2,
    float* __restrict__ cb, float* __restrict__ b1c, float* __restrict__ W2c,
    int* __restrict__ flags)
{
    const int k = blockIdx.x;   // input channel 0..127
    const int j = threadIdx.x;  // output channel
    if (j < 128) {
        float a = 0.f, b = 0.f;
        #pragma unroll 4
        for (int m = 0; m < 128; ++m) {
            a = fmaf(node_W[k * 128 + m], enc_W[m * 128 + j], a);
            b = fmaf(gud_W [k * 128 + m], enc_W[(256 + m) * 128 + j], b);
        }
        size_t i1 = (size_t)j * 128 + k;          // B^T[n=j][k]
        split3(a, BTn0[i1], BTn1[i1], BTn2[i1]);
        split3(b, BTg0[i1], BTg1[i1], BTg2[i1]);
    } else {
        const int n = j - 128;
        float a = 0.f;
        #pragma unroll 4
        for (int m = 0; m < 128; ++m)
            a = fmaf(nbr_W[k * 128 + m], enc_W[(128 + m) * 128 + n], a);
        size_t i2 = (size_t)(128 + n) * 128 + k;  // B^T[n=128+n][k]
        split3(a, BTn0[i2], BTn1[i2], BTn2[i2]);
    }
    if (j < 192) {
        float wv = (j < 64) ? vp_W1[k * 64 + j] : pol_W1[k * 128 + (j - 64)];
        size_t iw = (size_t)j * 128 + k;
        split3(wv, BTw0[iw], BTw1[iw], BTw2[iw]);
    }
    if (k == 0) {
        if (j < 128) {
            float cc = enc_b[j];
            for (int m = 0; m < 128; ++m) {
                cc = fmaf(node_b[m], enc_W[m * 128 + j], cc);
                cc = fmaf(nbr_b [m], enc_W[(128 + m) * 128 + j], cc);
                cc = fmaf(gud_b [m], enc_W[(256 + m) * 128 + j], cc);
            }
            cb[j] = cc;
        }
        if (j < 192) {
            b1c[j] = (j < 64) ? vp_b1[j] : pol_b1[j - 64];
            W2c[j] = (j < 64) ? vp_W2[j] : pol_W2[j - 64];
        }
        // --- runtime C/D orientation probe (wave 0) ---
        // A[m][0]=m+1, A[m][1]=1 ; B[0][n]=1, B[1][n]=100(n+1)  (bf16-exact)
        // => D[m][n] = (m+1) + 100(n+1), unique decode of (m,n).
        if (j < 64) {
            const int l = j, li = l & 15, lq = l >> 4;
            U8 A, B;
            #pragma unroll
            for (int u = 0; u < 8; ++u) { A.u[u] = 0; B.u[u] = 0; }
            if (lq == 0) {
                A.u[0] = bf16_rn((float)(li + 1));
                A.u[1] = bf16_rn(1.0f);
                B.u[0] = bf16_rn(1.0f);
                B.u[1] = bf16_rn((float)(100 * (li + 1)));
            }
            float4_t d = (float4_t){0.f, 0.f, 0.f, 0.f};
            d = __builtin_amdgcn_mfma_f32_16x16x32_bf16(A.v, B.v, d, 0, 0, 0);
            if (l == 17) {
                // assumed (m=lq*4+r, n=li): reg2 -> (6,1) -> 207
                // swapped (m=li, n=lq*4+r): reg2 -> (1,6) -> 702
                flags[0] = (fabsf(d[2] - 702.f) < 1.0f) ? 1 : 0;
            }
        }
    }
}

// ---------------------------------------------------------------------------
// node_kernel: 64 nodes/block; wave w handles N-tiles nt0..nt0+3 of the
// combined 256-wide output (w<2 -> P, w>=2 -> Q). Q-waves run kc 0..7
// (x@F2 then g@F3).
// ---------------------------------------------------------------------------
__global__ __launch_bounds__(256, 2) void node_kernel(
    const float* __restrict__ x, const float* __restrict__ g,
    const unsigned short* __restrict__ BTn0, const unsigned short* __restrict__ BTn1,
    const unsigned short* __restrict__ BTn2,
    const unsigned short* __restrict__ BTg0, const unsigned short* __restrict__ BTg1,
    const unsigned short* __restrict__ BTg2,
    const float* __restrict__ cb, const int* __restrict__ flags,
    float* __restrict__ P, float* __restrict__ Q)
{
    const int t = threadIdx.x;
    const int w = t >> 6, lane = t & 63;
    const int i16 = lane & 15, q = lane >> 4;
    const int base = blockIdx.x * 64;
    const bool qhalf = (w >= 2);
    const int nt0 = w * 4;
    const int kcmax = qhalf ? 8 : 4;
    const int swap = flags[0];

    float4_t acc[4][4];
    #pragma unroll
    for (int mt = 0; mt < 4; ++mt)
        #pragma unroll
        for (int nt = 0; nt < 4; ++nt) acc[mt][nt] = (float4_t){0.f, 0.f, 0.f, 0.f};

    for (int kc = 0; kc < kcmax; ++kc) {
        short8_t b0[4], b1v[4], b2v[4];
        #pragma unroll
        for (int nt = 0; nt < 4; ++nt) {
            if (kc < 4) {
                size_t roff = ((size_t)((nt0 + nt) * 16 + i16)) * 128 + kc * 32 + q * 8;
                b0[nt]  = *(const short8_t*)(BTn0 + roff);
                b1v[nt] = *(const short8_t*)(BTn1 + roff);
                b2v[nt] = *(const short8_t*)(BTn2 + roff);
            } else {
                size_t roff = ((size_t)((nt0 + nt - 8) * 16 + i16)) * 128 + (kc - 4) * 32 + q * 8;
                b0[nt]  = *(const short8_t*)(BTg0 + roff);
                b1v[nt] = *(const short8_t*)(BTg1 + roff);
                b2v[nt] = *(const short8_t*)(BTg2 + roff);
            }
        }
        #pragma unroll
        for (int mt = 0; mt < 4; ++mt) {
            int node = base + mt * 16 + i16; if (node > N_NODES - 1) node = N_NODES - 1;
            const float* src = (kc < 4)
                ? (x + (size_t)node * 128 + kc * 32 + q * 8)
                : (g + (size_t)node * 128 + (kc - 4) * 32 + q * 8);
            float4 v0 = *(const float4*)(src);
            float4 v1 = *(const float4*)(src + 4);
            float e[8] = {v0.x, v0.y, v0.z, v0.w, v1.x, v1.y, v1.z, v1.w};
            U8 a0, a1, a2;
            #pragma unroll
            for (int u = 0; u < 8; ++u) split3(e[u], a0.u[u], a1.u[u], a2.u[u]);
            #pragma unroll
            for (int nt = 0; nt < 4; ++nt) {
                float4_t c = acc[mt][nt];
                c = __builtin_amdgcn_mfma_f32_16x16x32_bf16(a0.v, b0[nt],  c, 0, 0, 0);
                c = __builtin_amdgcn_mfma_f32_16x16x32_bf16(a0.v, b1v[nt], c, 0, 0, 0);
                c = __builtin_amdgcn_mfma_f32_16x16x32_bf16(a1.v, b0[nt],  c, 0, 0, 0);
                c = __builtin_amdgcn_mfma_f32_16x16x32_bf16(a0.v, b2v[nt], c, 0, 0, 0);
                c = __builtin_amdgcn_mfma_f32_16x16x32_bf16(a1.v, b1v[nt], c, 0, 0, 0);
                c = __builtin_amdgcn_mfma_f32_16x16x32_bf16(a2.v, b0[nt],  c, 0, 0, 0);
                acc[mt][nt] = c;
            }
        }
    }

    if (!swap) {
        // value(lane q,i16; reg r) = C[node_l = mt*16+q*4+r][chan = T*16+i16]
        #pragma unroll
        for (int mt = 0; mt < 4; ++mt)
            #pragma unroll
            for (int nt = 0; nt < 4; ++nt) {
                int chan = (nt0 + nt) * 16 + i16;
                float bias = qhalf ? 0.f : cb[chan];
                #pragma unroll
                for (int r = 0; r < 4; ++r) {
                    int node = base + mt * 16 + q * 4 + r;
                    if (node < N_NODES) {
                        if (!qhalf) P[(size_t)node * 128 + chan] = acc[mt][nt][r] + bias;
                        else        Q[(size_t)node * 128 + (chan - 128)] = acc[mt][nt][r];
                    }
                }
            }
    } else {
        // value(lane q,i16; reg r) = C[node_l = mt*16+i16][chan = T*16+q*4+r]
        #pragma unroll
        for (int mt = 0; mt < 4; ++mt) {
            int node = base + mt * 16 + i16;
            if (node < N_NODES) {
                #pragma unroll
                for (int nt = 0; nt < 4; ++nt) {
                    int chanb = (nt0 + nt) * 16 + q * 4;
                    float4 vv;
                    vv.x = acc[mt][nt][0] + (!qhalf ? cb[chanb + 0] : 0.f);
                    vv.y = acc[mt][nt][1] + (!qhalf ? cb[chanb + 1] : 0.f);
                    vv.z = acc[mt][nt][2] + (!qhalf ? cb[chanb + 2] : 0.f);
                    vv.w = acc[mt][nt][3] + (!qhalf ? cb[chanb + 3] : 0.f);
                    if (!qhalf) *(float4*)(P + (size_t)node * 128 + chanb) = vv;
                    else        *(float4*)(Q + (size_t)node * 128 + chanb - 128) = vv;
                }
            }
        }
    }
}

// ---------------------------------------------------------------------------
// edge_kernel: 128 edges/block -> 8 M-tiles of 16 (THE round-3/4 bug: only 4
// were computed, leaving half of vpart uninitialized). Per kc: build
// enc=relu(P[row]+Q[col]) 3-split into LDS A-frag layout [quad][edge][8];
// waves n-split (3 of 12 N-tiles); B-frags from plain B^T in global.
// 800000 = 6250*128.
// ---------------------------------------------------------------------------
__global__ __launch_bounds__(256, 2) void edge_kernel(
    const int* __restrict__ ei,
    const float* __restrict__ P, const float* __restrict__ Q,
    const unsigned short* __restrict__ BTw0, const unsigned short* __restrict__ BTw1,
    const unsigned short* __restrict__ BTw2,
    const float* __restrict__ b1c, const float* __restrict__ W2c,
    const float* __restrict__ vp_b2, const float* __restrict__ pol_b2,
    const int* __restrict__ flags,
    float* __restrict__ out)
{
    __shared__ unsigned short enc0[4 * 128 * 8];
    __shared__ unsigned short enc1[4 * 128 * 8];
    __shared__ unsigned short enc2[4 * 128 * 8];
    __shared__ int rows_s[128], cols_s[128];
    __shared__ float vpart[512], ppart[512];

    const int t = threadIdx.x;
    const int w = t >> 6, lane = t & 63;
    const int i16 = lane & 15, q = lane >> 4;
    const int e0 = blockIdx.x * 128;
    const int ntg0 = w * 3;
    const int el = t & 127, hh = t >> 7;
    const int swap = flags[0];

    if (t < 128) rows_s[t] = ei[e0 + t];
    else         cols_s[t - 128] = ei[N_EDGES + e0 + (t - 128)];

    float4_t acc[8][3];
    #pragma unroll
    for (int mt = 0; mt < 8; ++mt)
        #pragma unroll
        for (int nt = 0; nt < 3; ++nt) acc[mt][nt] = (float4_t){0.f, 0.f, 0.f, 0.f};

    for (int kc = 0; kc < 4; ++kc) {
        __syncthreads();   // prior kc's A-frag reads done (covers rows_s init)
        {   // phase 1: thread (el, hh) builds 16 channels of edge el
            const float* Pp = P + (size_t)rows_s[el] * 128 + kc * 32 + hh * 16;
            const float* Qp = Q + (size_t)cols_s[el] * 128 + kc * 32 + hh * 16;
            U8 g0[2], g1[2], g2[2];
            #pragma unroll
            for (int i = 0; i < 4; ++i) {
                float4 pv = *(const float4*)(Pp + i * 4);
                float4 qv = *(const float4*)(Qp + i * 4);
                float ev[4] = {fmaxf(pv.x + qv.x, 0.f), fmaxf(pv.y + qv.y, 0.f),
                               fmaxf(pv.z + qv.z, 0.f), fmaxf(pv.w + qv.w, 0.f)};
                #pragma unroll
                for (int u = 0; u < 4; ++u) {
                    int idx = i * 4 + u;
                    split3(ev[u], g0[idx >> 3].u[idx & 7], g1[idx >> 3].u[idx & 7],
                           g2[idx >> 3].u[idx & 7]);
                }
            }
            #pragma unroll
            for (int hb = 0; hb < 2; ++hb) {
                size_t off = ((size_t)(2 * hh + hb) * 128 + el) * 8;
                *(short8_t*)(enc0 + off) = g0[hb].v;
                *(short8_t*)(enc1 + off) = g1[hb].v;
                *(short8_t*)(enc2 + off) = g2[hb].v;
            }
        }
        __syncthreads();
        short8_t b0[3], b1f[3], b2f[3];
        #pragma unroll
        for (int ntl = 0; ntl < 3; ++ntl) {
            size_t roff = ((size_t)((ntg0 + ntl) * 16 + i16)) * 128 + kc * 32 + q * 8;
            b0[ntl]  = *(const short8_t*)(BTw0 + roff);
            b1f[ntl] = *(const short8_t*)(BTw1 + roff);
            b2f[ntl] = *(const short8_t*)(BTw2 + roff);
        }
        #pragma unroll
        for (int mt = 0; mt < 8; ++mt) {
            size_t aoff = ((size_t)q * 128 + mt * 16 + i16) * 8;
            short8_t a0 = *(const short8_t*)(enc0 + aoff);
            short8_t a1 = *(const short8_t*)(enc1 + aoff);
            short8_t a2 = *(const short8_t*)(enc2 + aoff);
            #pragma unroll
            for (int ntl = 0; ntl < 3; ++ntl) {
                float4_t c = acc[mt][ntl];
                c = __builtin_amdgcn_mfma_f32_16x16x32_bf16(a0, b0[ntl],  c, 0, 0, 0);
                c = __builtin_amdgcn_mfma_f32_16x16x32_bf16(a0, b1f[ntl], c, 0, 0, 0);
                c = __builtin_amdgcn_mfma_f32_16x16x32_bf16(a1, b0[ntl],  c, 0, 0, 0);
                c = __builtin_amdgcn_mfma_f32_16x16x32_bf16(a0, b2f[ntl], c, 0, 0, 0);
                c = __builtin_amdgcn_mfma_f32_16x16x32_bf16(a1, b1f[ntl], c, 0, 0, 0);
                c = __builtin_amdgcn_mfma_f32_16x16x32_bf16(a2, b0[ntl],  c, 0, 0, 0);
                acc[mt][ntl] = c;
            }
        }
    }

    // epilogue: bias+relu+W2 per channel, reduce over the 16 channels/tile,
    // combine waves via LDS. Dual-path per probed C/D orientation.
    if (!swap) {
        // rows m=q*4+r (edges), cols n=i16 (channels): reduce over i16
        #pragma unroll
        for (int mt = 0; mt < 8; ++mt) {
            float vs[4] = {0.f, 0.f, 0.f, 0.f}, ps[4] = {0.f, 0.f, 0.f, 0.f};
            #pragma unroll
            for (int ntl = 0; ntl < 3; ++ntl) {
                int ntg = ntg0 + ntl;
                int n = ntg * 16 + i16;
                float b1s = b1c[n], w2s = W2c[n];
                bool isv = (ntg < 4);
                #pragma unroll
                for (int r = 0; r < 4; ++r) {
                    float hv = fmaxf(acc[mt][ntl][r] + b1s, 0.f) * w2s;
                    if (isv) vs[r] += hv; else ps[r] += hv;
                }
            }
            #pragma unroll
            for (int off = 1; off < 16; off <<= 1)
                #pragma unroll
                for (int r = 0; r < 4; ++r) {
                    vs[r] += __shfl_xor(vs[r], off, 64);
                    ps[r] += __shfl_xor(ps[r], off, 64);
                }
            if (i16 == 0)
                #pragma unroll
                for (int r = 0; r < 4; ++r) {
                    int eidx = mt * 16 + q * 4 + r;
                    vpart[w * 128 + eidx] = vs[r];
                    ppart[w * 128 + eidx] = ps[r];
                }
        }
    } else {
        // rows m=i16 (edges), cols n=q*4+r (channels): reduce over q
        #pragma unroll
        for (int mt = 0; mt < 8; ++mt) {
            float v = 0.f, p = 0.f;
            #pragma unroll
            for (int ntl = 0; ntl < 3; ++ntl) {
                int ntg = ntg0 + ntl;
                bool isv = (ntg < 4);
                #pragma unroll
                for (int r = 0; r < 4; ++r) {
                    int n = ntg * 16 + q * 4 + r;
                    float hv = fmaxf(acc[mt][ntl][r] + b1c[n], 0.f) * W2c[n];
                    if (isv) v += hv; else p += hv;
                }
            }
            v += __shfl_xor(v, 16, 64); v += __shfl_xor(v, 32, 64);
            p += __shfl_xor(p, 16, 64); p += __shfl_xor(p, 32, 64);
            if (q == 0) {
                int eidx = mt * 16 + i16;
                vpart[w * 128 + eidx] = v;
                ppart[w * 128 + eidx] = p;
            }
        }
    }
    __syncthreads();
    if (t < 128) {
        float v  = vpart[t] + vpart[128 + t] + vpart[256 + t] + vpart[384 + t] + vp_b2[0];
        float pl = ppart[t] + ppart[128 + t] + ppart[256 + t] + ppart[384 + t] + pol_b2[0];
        float prob = 1.0f / (1.0f + expf(-pl));
        int e = e0 + t;
        out[e] = v;
        out[N_EDGES + e] = prob;
        out[2 * N_EDGES + e] = (prob > 0.5f) ? 1.0f : 0.0f;
    }
    if (blockIdx.x == 0 && t == 0) out[3 * N_EDGES] = 0.0f;
}

extern "C" void kernel_launch(void* const* d_in, const int* in_sizes, int n_in,
                              void* d_out, int out_size, void* d_ws, size_t ws_size,
                              hipStream_t stream) {
    const float* x      = (const float*)d_in[0];
    const int*   ei     = (const int*)  d_in[1];
    const float* gf     = (const float*)d_in[2];
    const float* node_W = (const float*)d_in[3];
    const float* node_b = (const float*)d_in[4];
    const float* nbr_W  = (const float*)d_in[5];
    const float* nbr_b  = (const float*)d_in[6];
    const float* gud_W  = (const float*)d_in[7];
    const float* gud_b  = (const float*)d_in[8];
    const float* enc_W  = (const float*)d_in[9];
    const float* enc_b  = (const float*)d_in[10];
    const float* vp_W1  = (const float*)d_in[11];
    const float* vp_b1  = (const float*)d_in[12];
    const float* vp_W2  = (const float*)d_in[13];
    const float* vp_b2  = (const float*)d_in[14];
    const float* pol_W1 = (const float*)d_in[15];
    const float* pol_b1 = (const float*)d_in[16];
    const float* pol_W2 = (const float*)d_in[17];
    const float* pol_b2 = (const float*)d_in[18];
    float* out = (float*)d_out;

    unsigned char* wsb = (unsigned char*)d_ws;
    unsigned short* BTn0 = (unsigned short*)(wsb + 0);
    unsigned short* BTn1 = (unsigned short*)(wsb + 65536);
    unsigned short* BTn2 = (unsigned short*)(wsb + 131072);
    unsigned short* BTg0 = (unsigned short*)(wsb + 196608);
    unsigned short* BTg1 = (unsigned short*)(wsb + 229376);
    unsigned short* BTg2 = (unsigned short*)(wsb + 262144);
    unsigned short* BTw0 = (unsigned short*)(wsb + 294912);
    unsigned short* BTw1 = (unsigned short*)(wsb + 344064);
    unsigned short* BTw2 = (unsigned short*)(wsb + 393216);
    float* cb   = (float*)(wsb + 442368);
    float* b1c  = (float*)(wsb + 442880);
    float* W2c  = (float*)(wsb + 443648);
    int*   flags= (int*)  (wsb + 444416);
    float* Pd   = (float*)(wsb + 444480);
    float* Qd   = Pd + (size_t)N_NODES * 128;

    prep_kernel<<<dim3(128), dim3(256), 0, stream>>>(
        node_W, node_b, nbr_W, nbr_b, gud_W, gud_b, enc_W, enc_b,
        vp_W1, vp_b1, vp_W2, pol_W1, pol_b1, pol_W2,
        BTn0, BTn1, BTn2, BTg0, BTg1, BTg2, BTw0, BTw1, BTw2,
        cb, b1c, W2c, flags);

    node_kernel<<<dim3((N_NODES + 63) / 64), dim3(256), 0, stream>>>(
        x, gf, BTn0, BTn1, BTn2, BTg0, BTg1, BTg2, cb, flags, Pd, Qd);

    edge_kernel<<<dim3(N_EDGES / 128), dim3(256), 0, stream>>>(
        ei, Pd, Qd, BTw0, BTw1, BTw2, b1c, W2c, vp_b2, pol_b2, flags, out);
}

// Round 6
// 518.885 us; speedup vs baseline: 3.7119x; 1.1348x over previous
//
#include <hip/hip_runtime.h>
#include <math.h>

#define N_NODES 50000
#define N_EDGES 800000

// fp32 = a0+a1+a2 (3 bf16 terms). 6 MFMA term-pairs per product -> fp32-class
// numerics on the bf16 matrix core (~2^-24 relative with trunc-split).
typedef __attribute__((ext_vector_type(8))) short short8_t;   // bf16x8 (4 VGPR)
typedef __attribute__((ext_vector_type(4))) float float4_t;   // fp32x4 acc

union U8 { short8_t v; unsigned short u[8]; };

__device__ __forceinline__ unsigned short bf16_rn(float f) {
    unsigned u = __float_as_uint(f);
    u += 0x7fffu + ((u >> 16) & 1u);
    return (unsigned short)(u >> 16);
}
__device__ __forceinline__ float bf2f(unsigned short h) {
    return __uint_as_float((unsigned)h << 16);
}
// round-to-nearest split (prep only; max precision for reused weights)
__device__ __forceinline__ void split3(float f, unsigned short& s0,
                                       unsigned short& s1, unsigned short& s2) {
    s0 = bf16_rn(f);  float r = f - bf2f(s0);
    s1 = bf16_rn(r);  r -= bf2f(s1);
    s2 = bf16_rn(r);
}
// truncation split (hot kernels): trunc/sub are EXACT, only s2 rounds.
// f = s0+s1+s2 + err, |err| <= 2^-25|f|. 8 VALU ops vs ~16 for rn-split.
__device__ __forceinline__ void split3t(float f, unsigned short& s0,
                                        unsigned short& s1, unsigned short& s2) {
    unsigned u = __float_as_uint(f);
    s0 = (unsigned short)(u >> 16);
    float r = f - bf2f(s0);            // exact
    unsigned v = __float_as_uint(r);
    s1 = (unsigned short)(v >> 16);
    float r2 = r - bf2f(s1);           // exact
    s2 = bf16_rn(r2);
}

// ---------------------------------------------------------------------------
// ws layout (bytes):
//   BTn0/1/2 [256][128] bf16 : rows 0..127 = F1^T (P), 128..255 = F2^T (Q,x)
//   BTg0/1/2 [128][128] bf16 : F3^T (Q,g)
//   BTw0/1/2 [192][128] bf16 : [vp_W1 | pol_W1]^T
//   cb[128] folded bias (into P), b1c[192], W2c[192], flags[16]
//   P[50000*128] = x@F1 + cb ; Q[50000*128] = x@F2 + g@F3
// ---------------------------------------------------------------------------

__global__ __launch_bounds__(256) void prep_kernel(
    const float* __restrict__ node_W, const float* __restrict__ node_b,
    const float* __restrict__ nbr_W,  const float* __restrict__ nbr_b,
    const float* __restrict__ gud_W,  const float* __restrict__ gud_b,
    const float* __restrict__ enc_W,  const float* __restrict__ enc_b,
    const float* __restrict__ vp_W1,  const float* __restrict__ vp_b1,
    const float* __restrict__ vp_W2,  const float* __restrict__ pol_W1,
    const float* __restrict__ pol_b1, const float* __restrict__ pol_W2,
    unsigned short* __restrict__ BTn0, unsigned short* __restrict__ BTn1,
    unsigned short* __restrict__ BTn2,
    unsigned short* __restrict__ BTg0, unsigned short* __restrict__ BTg1,
    unsigned short* __restrict__ BTg2,
    unsigned short* __restrict__ BTw0, unsigned short* __restrict__ BTw1,
    unsigned short* __restrict__ BTw2,
    float* __restrict__ cb, float* __restrict__ b1c, float* __restrict__ W2c,
    int* __restrict__ flags)
{
    const int k = blockIdx.x;   // input channel 0..127
    const int j = threadIdx.x;  // output channel
    if (j < 128) {
        float a = 0.f, b = 0.f;
        #pragma unroll 4
        for (int m = 0; m < 128; ++m) {
            a = fmaf(node_W[k * 128 + m], enc_W[m * 128 + j], a);
            b = fmaf(gud_W [k * 128 + m], enc_W[(256 + m) * 128 + j], b);
        }
        size_t i1 = (size_t)j * 128 + k;          // B^T[n=j][k]
        split3(a, BTn0[i1], BTn1[i1], BTn2[i1]);
        split3(b, BTg0[i1], BTg1[i1], BTg2[i1]);
    } else {
        const int n = j - 128;
        float a = 0.f;
        #pragma unroll 4
        for (int m = 0; m < 128; ++m)
            a = fmaf(nbr_W[k * 128 + m], enc_W[(128 + m) * 128 + n], a);
        size_t i2 = (size_t)(128 + n) * 128 + k;  // B^T[n=128+n][k]
        split3(a, BTn0[i2], BTn1[i2], BTn2[i2]);
    }
    if (j < 192) {
        float wv = (j < 64) ? vp_W1[k * 64 + j] : pol_W1[k * 128 + (j - 64)];
        size_t iw = (size_t)j * 128 + k;
        split3(wv, BTw0[iw], BTw1[iw], BTw2[iw]);
    }
    if (k == 0) {
        if (j < 128) {
            float cc = enc_b[j];
            for (int m = 0; m < 128; ++m) {
                cc = fmaf(node_b[m], enc_W[m * 128 + j], cc);
                cc = fmaf(nbr_b [m], enc_W[(128 + m) * 128 + j], cc);
                cc = fmaf(gud_b [m], enc_W[(256 + m) * 128 + j], cc);
            }
            cb[j] = cc;
        }
        if (j < 192) {
            b1c[j] = (j < 64) ? vp_b1[j] : pol_b1[j - 64];
            W2c[j] = (j < 64) ? vp_W2[j] : pol_W2[j - 64];
        }
        // --- runtime C/D orientation probe (wave 0), verified round 5 ---
        if (j < 64) {
            const int l = j, li = l & 15, lq = l >> 4;
            U8 A, B;
            #pragma unroll
            for (int u = 0; u < 8; ++u) { A.u[u] = 0; B.u[u] = 0; }
            if (lq == 0) {
                A.u[0] = bf16_rn((float)(li + 1));
                A.u[1] = bf16_rn(1.0f);
                B.u[0] = bf16_rn(1.0f);
                B.u[1] = bf16_rn((float)(100 * (li + 1)));
            }
            float4_t d = (float4_t){0.f, 0.f, 0.f, 0.f};
            d = __builtin_amdgcn_mfma_f32_16x16x32_bf16(A.v, B.v, d, 0, 0, 0);
            if (l == 17) {
                flags[0] = (fabsf(d[2] - 702.f) < 1.0f) ? 1 : 0;
            }
        }
    }
}

// ---------------------------------------------------------------------------
// node_kernel: 64 nodes/block. x/g split ONCE per block into LDS (round 5 did
// it per-wave: 4x the VALU + 4x the traffic). Striped N ownership: wave w owns
// global N-tiles {w, w+4, w+8, w+12} so all waves stay busy in the g-phase
// (only Q tiles 8..15 active for kc>=4). Gather prefetch pipelines the x/g
// loads under the MFMA phase.
// ---------------------------------------------------------------------------
__global__ __launch_bounds__(256, 3) void node_kernel(
    const float* __restrict__ x, const float* __restrict__ g,
    const unsigned short* __restrict__ BTn0, const unsigned short* __restrict__ BTn1,
    const unsigned short* __restrict__ BTn2,
    const unsigned short* __restrict__ BTg0, const unsigned short* __restrict__ BTg1,
    const unsigned short* __restrict__ BTg2,
    const float* __restrict__ cb, const int* __restrict__ flags,
    float* __restrict__ P, float* __restrict__ Q)
{
    __shared__ unsigned short a0s[4 * 64 * 8];   // [k-sub][node][8]
    __shared__ unsigned short a1s[4 * 64 * 8];
    __shared__ unsigned short a2s[4 * 64 * 8];
    const int t = threadIdx.x;
    const int w = t >> 6, lane = t & 63;
    const int i16 = lane & 15, q = lane >> 4;
    const int base = blockIdx.x * 64;
    const int swap = flags[0];
    // staging role: 4 threads/node, 8 channels each; lanes 4k..4k+3 read a
    // contiguous 128 B row segment.
    const int el = t >> 2, hh = t & 3;
    int nodeL = base + el; if (nodeL > N_NODES - 1) nodeL = N_NODES - 1;
    const float* xrow = x + (size_t)nodeL * 128 + hh * 8;
    const float* grow = g + (size_t)nodeL * 128 + hh * 8;

    float4_t acc[4][4];
    #pragma unroll
    for (int mt = 0; mt < 4; ++mt)
        #pragma unroll
        for (int nt = 0; nt < 4; ++nt) acc[mt][nt] = (float4_t){0.f, 0.f, 0.f, 0.f};

    float4 pv0 = *(const float4*)(xrow);
    float4 pv1 = *(const float4*)(xrow + 4);

    for (int kc = 0; kc < 8; ++kc) {
        // split prefetched values (VALU only, before barrier)
        U8 s0, s1, s2;
        {
            float e[8] = {pv0.x, pv0.y, pv0.z, pv0.w, pv1.x, pv1.y, pv1.z, pv1.w};
            #pragma unroll
            for (int u = 0; u < 8; ++u) split3t(e[u], s0.u[u], s1.u[u], s2.u[u]);
        }
        __syncthreads();   // prior kc's A-frag reads done
        {
            size_t off = ((size_t)hh * 64 + el) * 8;
            *(short8_t*)(a0s + off) = s0.v;
            *(short8_t*)(a1s + off) = s1.v;
            *(short8_t*)(a2s + off) = s2.v;
        }
        __syncthreads();
        if (kc < 7) {   // prefetch next chunk under the MFMA phase
            const float* nsrc = (kc + 1 < 4) ? (xrow + (kc + 1) * 32)
                                             : (grow + (kc + 1 - 4) * 32);
            pv0 = *(const float4*)(nsrc);
            pv1 = *(const float4*)(nsrc + 4);
        }
        if (kc < 4) {
            short8_t b0[4], b1v[4], b2v[4];
            #pragma unroll
            for (int ntl = 0; ntl < 4; ++ntl) {
                int ntg = w + ntl * 4;
                size_t roff = ((size_t)(ntg * 16 + i16)) * 128 + kc * 32 + q * 8;
                b0[ntl]  = *(const short8_t*)(BTn0 + roff);
                b1v[ntl] = *(const short8_t*)(BTn1 + roff);
                b2v[ntl] = *(const short8_t*)(BTn2 + roff);
            }
            #pragma unroll
            for (int mt = 0; mt < 4; ++mt) {
                size_t aoff = ((size_t)q * 64 + mt * 16 + i16) * 8;
                short8_t a0 = *(const short8_t*)(a0s + aoff);
                short8_t a1 = *(const short8_t*)(a1s + aoff);
                short8_t a2 = *(const short8_t*)(a2s + aoff);
                #pragma unroll
                for (int ntl = 0; ntl < 4; ++ntl) {
                    float4_t c = acc[mt][ntl];
                    c = __builtin_amdgcn_mfma_f32_16x16x32_bf16(a0, b0[ntl],  c, 0, 0, 0);
                    c = __builtin_amdgcn_mfma_f32_16x16x32_bf16(a0, b1v[ntl], c, 0, 0, 0);
                    c = __builtin_amdgcn_mfma_f32_16x16x32_bf16(a1, b0[ntl],  c, 0, 0, 0);
                    c = __builtin_amdgcn_mfma_f32_16x16x32_bf16(a0, b2v[ntl], c, 0, 0, 0);
                    c = __builtin_amdgcn_mfma_f32_16x16x32_bf16(a1, b1v[ntl], c, 0, 0, 0);
                    c = __builtin_amdgcn_mfma_f32_16x16x32_bf16(a2, b0[ntl],  c, 0, 0, 0);
                    acc[mt][ntl] = c;
                }
            }
        } else {
            short8_t b0[2], b1v[2], b2v[2];
            #pragma unroll
            for (int ntl = 0; ntl < 2; ++ntl) {
                int ntg = w + (ntl + 2) * 4;   // Q tiles w+8, w+12
                size_t roff = ((size_t)((ntg - 8) * 16 + i16)) * 128 + (kc - 4) * 32 + q * 8;
                b0[ntl]  = *(const short8_t*)(BTg0 + roff);
                b1v[ntl] = *(const short8_t*)(BTg1 + roff);
                b2v[ntl] = *(const short8_t*)(BTg2 + roff);
            }
            #pragma unroll
            for (int mt = 0; mt < 4; ++mt) {
                size_t aoff = ((size_t)q * 64 + mt * 16 + i16) * 8;
                short8_t a0 = *(const short8_t*)(a0s + aoff);
                short8_t a1 = *(const short8_t*)(a1s + aoff);
                short8_t a2 = *(const short8_t*)(a2s + aoff);
                #pragma unroll
                for (int ntl = 0; ntl < 2; ++ntl) {
                    float4_t c = acc[mt][ntl + 2];
                    c = __builtin_amdgcn_mfma_f32_16x16x32_bf16(a0, b0[ntl],  c, 0, 0, 0);
                    c = __builtin_amdgcn_mfma_f32_16x16x32_bf16(a0, b1v[ntl], c, 0, 0, 0);
                    c = __builtin_amdgcn_mfma_f32_16x16x32_bf16(a1, b0[ntl],  c, 0, 0, 0);
                    c = __builtin_amdgcn_mfma_f32_16x16x32_bf16(a0, b2v[ntl], c, 0, 0, 0);
                    c = __builtin_amdgcn_mfma_f32_16x16x32_bf16(a1, b1v[ntl], c, 0, 0, 0);
                    c = __builtin_amdgcn_mfma_f32_16x16x32_bf16(a2, b0[ntl],  c, 0, 0, 0);
                    acc[mt][ntl + 2] = c;
                }
            }
        }
    }

    if (!swap) {
        #pragma unroll
        for (int mt = 0; mt < 4; ++mt)
            #pragma unroll
            for (int ntl = 0; ntl < 4; ++ntl) {
                int ntg = w + ntl * 4;
                int chan = ntg * 16 + i16;
                bool isP = (ntg < 8);
                float bias = isP ? cb[chan] : 0.f;
                #pragma unroll
                for (int r = 0; r < 4; ++r) {
                    int node = base + mt * 16 + q * 4 + r;
                    if (node < N_NODES) {
                        if (isP) P[(size_t)node * 128 + chan] = acc[mt][ntl][r] + bias;
                        else     Q[(size_t)node * 128 + (chan - 128)] = acc[mt][ntl][r];
                    }
                }
            }
    } else {
        #pragma unroll
        for (int mt = 0; mt < 4; ++mt) {
            int node = base + mt * 16 + i16;
            if (node < N_NODES) {
                #pragma unroll
                for (int ntl = 0; ntl < 4; ++ntl) {
                    int ntg = w + ntl * 4;
                    int chanb = ntg * 16 + q * 4;
                    bool isP = (ntg < 8);
                    float4 vv;
                    vv.x = acc[mt][ntl][0] + (isP ? cb[chanb + 0] : 0.f);
                    vv.y = acc[mt][ntl][1] + (isP ? cb[chanb + 1] : 0.f);
                    vv.z = acc[mt][ntl][2] + (isP ? cb[chanb + 2] : 0.f);
                    vv.w = acc[mt][ntl][3] + (isP ? cb[chanb + 3] : 0.f);
                    if (isP) *(float4*)(P + (size_t)node * 128 + chanb) = vv;
                    else     *(float4*)(Q + (size_t)node * 128 + chanb - 128) = vv;
                }
            }
        }
    }
}

// ---------------------------------------------------------------------------
// edge_kernel: 128 edges/block, 8 M-tiles. Software-pipelined gathers: the
// P[row]/Q[col] loads for kc+1 are issued right after the LDS-write barrier
// of kc so their latency sits under the 144-MFMA phase. rows/cols in regs.
// 800000 = 6250*128.
// ---------------------------------------------------------------------------
__global__ __launch_bounds__(256, 2) void edge_kernel(
    const int* __restrict__ ei,
    const float* __restrict__ P, const float* __restrict__ Q,
    const unsigned short* __restrict__ BTw0, const unsigned short* __restrict__ BTw1,
    const unsigned short* __restrict__ BTw2,
    const float* __restrict__ b1c, const float* __restrict__ W2c,
    const float* __restrict__ vp_b2, const float* __restrict__ pol_b2,
    const int* __restrict__ flags,
    float* __restrict__ out)
{
    __shared__ unsigned short enc0[4 * 128 * 8];
    __shared__ unsigned short enc1[4 * 128 * 8];
    __shared__ unsigned short enc2[4 * 128 * 8];
    __shared__ float vpart[512], ppart[512];

    const int t = threadIdx.x;
    const int w = t >> 6, lane = t & 63;
    const int i16 = lane & 15, q = lane >> 4;
    const int e0 = blockIdx.x * 128;
    const int ntg0 = w * 3;
    // staging role: 2 threads/edge (adjacent lanes -> one 128 B row segment)
    const int el = t >> 1, hh = t & 1;
    const int swap = flags[0];

    const int rowI = ei[e0 + el];
    const int colI = ei[N_EDGES + e0 + el];
    const float* Pp = P + (size_t)rowI * 128 + hh * 16;
    const float* Qp = Q + (size_t)colI * 128 + hh * 16;

    float4_t acc[8][3];
    #pragma unroll
    for (int mt = 0; mt < 8; ++mt)
        #pragma unroll
        for (int nt = 0; nt < 3; ++nt) acc[mt][nt] = (float4_t){0.f, 0.f, 0.f, 0.f};

    float4 pv[4], qv[4];
    #pragma unroll
    for (int i = 0; i < 4; ++i) {
        pv[i] = *(const float4*)(Pp + i * 4);
        qv[i] = *(const float4*)(Qp + i * 4);
    }

    for (int kc = 0; kc < 4; ++kc) {
        // build enc = relu(P+Q) and 3-split (VALU only, before barrier)
        U8 g0[2], g1[2], g2[2];
        #pragma unroll
        for (int i = 0; i < 4; ++i) {
            float ev[4] = {fmaxf(pv[i].x + qv[i].x, 0.f), fmaxf(pv[i].y + qv[i].y, 0.f),
                           fmaxf(pv[i].z + qv[i].z, 0.f), fmaxf(pv[i].w + qv[i].w, 0.f)};
            #pragma unroll
            for (int u = 0; u < 4; ++u) {
                int idx = i * 4 + u;
                split3t(ev[u], g0[idx >> 3].u[idx & 7], g1[idx >> 3].u[idx & 7],
                        g2[idx >> 3].u[idx & 7]);
            }
        }
        __syncthreads();   // prior kc's A-frag reads done
        #pragma unroll
        for (int hb = 0; hb < 2; ++hb) {
            size_t off = ((size_t)(2 * hh + hb) * 128 + el) * 8;
            *(short8_t*)(enc0 + off) = g0[hb].v;
            *(short8_t*)(enc1 + off) = g1[hb].v;
            *(short8_t*)(enc2 + off) = g2[hb].v;
        }
        __syncthreads();
        if (kc < 3) {   // prefetch kc+1 gathers under the MFMA phase
            #pragma unroll
            for (int i = 0; i < 4; ++i) {
                pv[i] = *(const float4*)(Pp + (kc + 1) * 32 + i * 4);
                qv[i] = *(const float4*)(Qp + (kc + 1) * 32 + i * 4);
            }
        }
        short8_t b0[3], b1f[3], b2f[3];
        #pragma unroll
        for (int ntl = 0; ntl < 3; ++ntl) {
            size_t roff = ((size_t)((ntg0 + ntl) * 16 + i16)) * 128 + kc * 32 + q * 8;
            b0[ntl]  = *(const short8_t*)(BTw0 + roff);
            b1f[ntl] = *(const short8_t*)(BTw1 + roff);
            b2f[ntl] = *(const short8_t*)(BTw2 + roff);
        }
        #pragma unroll
        for (int mt = 0; mt < 8; ++mt) {
            size_t aoff = ((size_t)q * 128 + mt * 16 + i16) * 8;
            short8_t a0 = *(const short8_t*)(enc0 + aoff);
            short8_t a1 = *(const short8_t*)(enc1 + aoff);
            short8_t a2 = *(const short8_t*)(enc2 + aoff);
            #pragma unroll
            for (int ntl = 0; ntl < 3; ++ntl) {
                float4_t c = acc[mt][ntl];
                c = __builtin_amdgcn_mfma_f32_16x16x32_bf16(a0, b0[ntl],  c, 0, 0, 0);
                c = __builtin_amdgcn_mfma_f32_16x16x32_bf16(a0, b1f[ntl], c, 0, 0, 0);
                c = __builtin_amdgcn_mfma_f32_16x16x32_bf16(a1, b0[ntl],  c, 0, 0, 0);
                c = __builtin_amdgcn_mfma_f32_16x16x32_bf16(a0, b2f[ntl], c, 0, 0, 0);
                c = __builtin_amdgcn_mfma_f32_16x16x32_bf16(a1, b1f[ntl], c, 0, 0, 0);
                c = __builtin_amdgcn_mfma_f32_16x16x32_bf16(a2, b0[ntl],  c, 0, 0, 0);
                acc[mt][ntl] = c;
            }
        }
    }

    // epilogue: bias+relu+W2, reduce, combine waves via LDS (dual-path)
    if (!swap) {
        #pragma unroll
        for (int mt = 0; mt < 8; ++mt) {
            float vs[4] = {0.f, 0.f, 0.f, 0.f}, ps[4] = {0.f, 0.f, 0.f, 0.f};
            #pragma unroll
            for (int ntl = 0; ntl < 3; ++ntl) {
                int ntg = ntg0 + ntl;
                int n = ntg * 16 + i16;
                float b1s = b1c[n], w2s = W2c[n];
                bool isv = (ntg < 4);
                #pragma unroll
                for (int r = 0; r < 4; ++r) {
                    float hv = fmaxf(acc[mt][ntl][r] + b1s, 0.f) * w2s;
                    if (isv) vs[r] += hv; else ps[r] += hv;
                }
            }
            #pragma unroll
            for (int off = 1; off < 16; off <<= 1)
                #pragma unroll
                for (int r = 0; r < 4; ++r) {
                    vs[r] += __shfl_xor(vs[r], off, 64);
                    ps[r] += __shfl_xor(ps[r], off, 64);
                }
            if (i16 == 0)
                #pragma unroll
                for (int r = 0; r < 4; ++r) {
                    int eidx = mt * 16 + q * 4 + r;
                    vpart[w * 128 + eidx] = vs[r];
                    ppart[w * 128 + eidx] = ps[r];
                }
        }
    } else {
        #pragma unroll
        for (int mt = 0; mt < 8; ++mt) {
            float v = 0.f, p = 0.f;
            #pragma unroll
            for (int ntl = 0; ntl < 3; ++ntl) {
                int ntg = ntg0 + ntl;
                bool isv = (ntg < 4);
                #pragma unroll
                for (int r = 0; r < 4; ++r) {
                    int n = ntg * 16 + q * 4 + r;
                    float hv = fmaxf(acc[mt][ntl][r] + b1c[n], 0.f) * W2c[n];
                    if (isv) v += hv; else p += hv;
                }
            }
            v += __shfl_xor(v, 16, 64); v += __shfl_xor(v, 32, 64);
            p += __shfl_xor(p, 16, 64); p += __shfl_xor(p, 32, 64);
            if (q == 0) {
                int eidx = mt * 16 + i16;
                vpart[w * 128 + eidx] = v;
                ppart[w * 128 + eidx] = p;
            }
        }
    }
    __syncthreads();
    if (t < 128) {
        float v  = vpart[t] + vpart[128 + t] + vpart[256 + t] + vpart[384 + t] + vp_b2[0];
        float pl = ppart[t] + ppart[128 + t] + ppart[256 + t] + ppart[384 + t] + pol_b2[0];
        float prob = 1.0f / (1.0f + expf(-pl));
        int e = e0 + t;
        out[e] = v;
        out[N_EDGES + e] = prob;
        out[2 * N_EDGES + e] = (prob > 0.5f) ? 1.0f : 0.0f;
    }
    if (blockIdx.x == 0 && t == 0) out[3 * N_EDGES] = 0.0f;
}

extern "C" void kernel_launch(void* const* d_in, const int* in_sizes, int n_in,
                              void* d_out, int out_size, void* d_ws, size_t ws_size,
                              hipStream_t stream) {
    const float* x      = (const float*)d_in[0];
    const int*   ei     = (const int*)  d_in[1];
    const float* gf     = (const float*)d_in[2];
    const float* node_W = (const float*)d_in[3];
    const float* node_b = (const float*)d_in[4];
    const float* nbr_W  = (const float*)d_in[5];
    const float* nbr_b  = (const float*)d_in[6];
    const float* gud_W  = (const float*)d_in[7];
    const float* gud_b  = (const float*)d_in[8];
    const float* enc_W  = (const float*)d_in[9];
    const float* enc_b  = (const float*)d_in[10];
    const float* vp_W1  = (const float*)d_in[11];
    const float* vp_b1  = (const float*)d_in[12];
    const float* vp_W2  = (const float*)d_in[13];
    const float* vp_b2  = (const float*)d_in[14];
    const float* pol_W1 = (const float*)d_in[15];
    const float* pol_b1 = (const float*)d_in[16];
    const float* pol_W2 = (const float*)d_in[17];
    const float* pol_b2 = (const float*)d_in[18];
    float* out = (float*)d_out;

    unsigned char* wsb = (unsigned char*)d_ws;
    unsigned short* BTn0 = (unsigned short*)(wsb + 0);
    unsigned short* BTn1 = (unsigned short*)(wsb + 65536);
    unsigned short* BTn2 = (unsigned short*)(wsb + 131072);
    unsigned short* BTg0 = (unsigned short*)(wsb + 196608);
    unsigned short* BTg1 = (unsigned short*)(wsb + 229376);
    unsigned short* BTg2 = (unsigned short*)(wsb + 262144);
    unsigned short* BTw0 = (unsigned short*)(wsb + 294912);
    unsigned short* BTw1 = (unsigned short*)(wsb + 344064);
    unsigned short* BTw2 = (unsigned short*)(wsb + 393216);
    float* cb   = (float*)(wsb + 442368);
    float* b1c  = (float*)(wsb + 442880);
    float* W2c  = (float*)(wsb + 443648);
    int*   flags= (int*)  (wsb + 444416);
    float* Pd   = (float*)(wsb + 444480);
    float* Qd   = Pd + (size_t)N_NODES * 128;

    prep_kernel<<<dim3(128), dim3(256), 0, stream>>>(
        node_W, node_b, nbr_W, nbr_b, gud_W, gud_b, enc_W, enc_b,
        vp_W1, vp_b1, vp_W2, pol_W1, pol_b1, pol_W2,
        BTn0, BTn1, BTn2, BTg0, BTg1, BTg2, BTw0, BTw1, BTw2,
        cb, b1c, W2c, flags);

    node_kernel<<<dim3((N_NODES + 63) / 64), dim3(256), 0, stream>>>(
        x, gf, BTn0, BTn1, BTn2, BTg0, BTg1, BTg2, cb, flags, Pd, Qd);

    edge_kernel<<<dim3(N_EDGES / 128), dim3(256), 0, stream>>>(
        ei, Pd, Qd, BTw0, BTw1, BTw2, b1c, W2c, vp_b2, pol_b2, flags, out);
}